// Round 7
// baseline (135.471 us; speedup 1.0000x reference)
//
#include <hip/hip_runtime.h>

// SimpleCRFHead R7: R5's PROVEN quad-split core (quad_perm DPP — explicit
// permutation, no direction ambiguity; passed absmax 0) + t-parallel path
// gathers and per-window batched exps (the R6 idea that was right, minus the
// unproven 16-lane ring).
// 4 lanes/seq (lane c owns states 3c..3c+2, c==3 pad), 16 seqs/wave,
// 1024 blocks x 64 threads (512 fwd + 512 bwd), window = 8 steps.
// Per window: lane c gathers path slots {8w+2c, 8w+2c+1} (parallel across
// lanes, <=2-deep dependence), 24 exps hoisted, then 8 chained matvec steps
// whose critical path is only QROT + two 6-deep FMA chains. Rescale per window.

#define B_N 8192
#define L_N 256
#define SEQ_STRIDE 2304      // L_N * 9
#define SPB 8                // steps per window
#define XW 72                // floats per seq per window (SPB*9)
#define XSTRIDE 73           // odd -> conflict-free LDS banks
#define NW 16                // windows (16*8 = 128 steps per direction)
#define PLS 129              // path LDS row stride
#define SPW 16               // seqs per wave
#define NDIR_BLOCKS (B_N / SPW)   // 512 per direction

#define LOG2E 1.44269504088896340736f
#define LN2f  0.69314718055994530942f

// quad_perm rotate-left-by-r: lane c receives quad-lane (c+r)&3  [R5-proven]
#define QP1 57    // perm(1,2,3,0)
#define QP2 78    // perm(2,3,0,1)
#define QP3 147   // perm(3,0,1,2)
#define QROT(src, CTRL) \
  __int_as_float(__builtin_amdgcn_mov_dpp(__float_as_int(src), CTRL, 0xf, 0xf, 0))

__device__ __forceinline__ void gl_lds4(const void* g, void* l) {
  __builtin_amdgcn_global_load_lds(
      (const __attribute__((address_space(1))) void*)g,
      (__attribute__((address_space(3))) void*)l, 4, 0, 0);
}

__device__ __forceinline__ float fexp(float x) {
  return __builtin_amdgcn_exp2f(x * LOG2E);   // v_exp_f32 = 2^x
}

__global__ __launch_bounds__(64) void crf_half(
    const float* __restrict__ xg, const int* __restrict__ path,
    const float* __restrict__ tran, const float* __restrict__ initv,
    float* __restrict__ ws)
{
  __shared__ float lx[2][SPW * XSTRIDE];  // 9344 B
  __shared__ int   pl[SPW * PLS];         // 8256 B
  __shared__ float ltran[81];             // ~18 KB total

  const int lane = threadIdx.x;
  const int c = lane & 3;                 // quad slot (state group)
  const int q = lane >> 2;                // seq slot within wave (0..15)
  const bool fwd = (int)blockIdx.x < NDIR_BLOCKS;
  const int seq0 = (fwd ? blockIdx.x : blockIdx.x - NDIR_BLOCKS) * SPW;

  for (int i = lane; i < 81; i += 64) ltran[i] = tran[i];

  // ---- stage path (slots: fwd s=t in [0,127]; bwd s=t-127 in [0,128])
  {
    const int t0 = fwd ? 0 : 127;
#pragma unroll
    for (int rr = 0; rr < SPW; ++rr) {
      const int* g = path + (size_t)(seq0 + rr) * L_N + t0;
      gl_lds4(g + lane, &pl[rr * PLS]);
      gl_lds4(g + 64 + lane, &pl[rr * PLS + 64]);
    }
  }
  if (!fwd && lane < SPW)
    pl[lane * PLS + 128] = path[(size_t)(seq0 + lane) * L_N + 255];

  // ---- stage first x window (fwd: w=0 -> buf0; bwd: w=15 -> buf1)
#define STAGE_X(FB, BI)                                                  \
  { _Pragma("unroll")                                                    \
    for (int rr = 0; rr < SPW; ++rr)                                     \
      gl_lds4(xg + (size_t)(seq0 + rr) * SEQ_STRIDE + (FB) + lane,       \
              &lx[(BI)][rr * XSTRIDE]);                                  \
    if (lane < XW - 64) {                                                \
      _Pragma("unroll")                                                  \
      for (int rr = 0; rr < SPW; ++rr)                                   \
        gl_lds4(xg + (size_t)(seq0 + rr) * SEQ_STRIDE + (FB) + 64 + lane,\
                &lx[(BI)][rr * XSTRIDE + 64]);                           \
    } }

  if (fwd) { STAGE_X(0, 0) } else { STAGE_X(1152 + 72 * 15, 1) }

  // ---- rotation-ordered transition coefficients (R5-proven layout)
  // fwd: out_i = sum_j E[i][j]*st[j], E[i][j]=e^{tran[j*9+i]}
  // bwd: out_i = sum_j E[i][j]*w[j],  E[i][j]=e^{tran[i*9+j]}
  float Erot[4][3][3];
#pragma unroll
  for (int r = 0; r < 4; ++r)
#pragma unroll
    for (int k = 0; k < 3; ++k)
#pragma unroll
      for (int i = 0; i < 3; ++i) {
        const int ig = 3 * c + i;
        const int jg = 3 * ((c + r) & 3) + k;
        float v = 0.f;
        if (ig < 9 && jg < 9)
          v = fexp(fwd ? tran[jg * 9 + ig] : tran[ig * 9 + jg]);
        Erot[r][k][i] = v;
      }

  float o[3];
  float emit = 0.f, trn = 0.f;
  int ce = 0;
  if (!fwd) {
#pragma unroll
    for (int k = 0; k < 3; ++k) o[k] = (c < 3) ? 1.f : 0.f;
  }

  const int myoff = (c == 3) ? 0 : 3 * c;
  const int plq = q * PLS;

  // one matvec step: IN -> o, with two 6-deep FMA chains per output
#define MATVEC(IN)                                                       \
  { float g1[3], g2[3], g3[3];                                           \
    _Pragma("unroll")                                                    \
    for (int k = 0; k < 3; ++k) {                                        \
      g1[k] = QROT(IN[k], QP1);                                          \
      g2[k] = QROT(IN[k], QP2);                                          \
      g3[k] = QROT(IN[k], QP3);                                          \
    }                                                                    \
    _Pragma("unroll")                                                    \
    for (int i = 0; i < 3; ++i) {                                        \
      float aA = Erot[0][0][i] * IN[0];                                  \
      aA = fmaf(Erot[0][1][i], IN[1], aA);                               \
      aA = fmaf(Erot[0][2][i], IN[2], aA);                               \
      aA = fmaf(Erot[1][0][i], g1[0], aA);                               \
      aA = fmaf(Erot[1][1][i], g1[1], aA);                               \
      aA = fmaf(Erot[1][2][i], g1[2], aA);                               \
      float aB = Erot[2][0][i] * g2[0];                                  \
      aB = fmaf(Erot[2][1][i], g2[1], aB);                               \
      aB = fmaf(Erot[2][2][i], g2[2], aB);                               \
      aB = fmaf(Erot[3][0][i], g3[0], aB);                               \
      aB = fmaf(Erot[3][1][i], g3[1], aB);                               \
      aB = fmaf(Erot[3][2][i], g3[2], aB);                               \
      nxt[i] = aA + aB;                                                  \
    } }

#define RESCALE()                                                        \
  { float m_ = fmaxf(fmaxf(o[0], o[1]), o[2]);                           \
    m_ = fmaxf(m_, QROT(m_, QP1));                                       \
    m_ = fmaxf(m_, QROT(m_, QP2));                                       \
    const int ex_ = (int)((__float_as_uint(m_) >> 23) & 0xffu) - 126;    \
    ce += ex_;                                                           \
    const float sc_ = __uint_as_float((unsigned)(127 - ex_) << 23);      \
    o[0] *= sc_; o[1] *= sc_; o[2] *= sc_; }

  if (fwd) {
#pragma unroll 1
    for (int w = 0; w < NW; ++w) {
      asm volatile("s_waitcnt vmcnt(0)" ::: "memory");
      if (w < NW - 1) { STAGE_X(72 * (w + 1), (w + 1) & 1) }
      const float* lxq = &lx[w & 1][q * XSTRIDE];

      // t-parallel path gathers: lane c handles slots s0=8w+2c, s1=s0+1
      {
        const int s0 = 8 * w + 2 * c;
        const int ps0 = pl[plq + s0];
        const int ps1 = pl[plq + s0 + 1];
        const int pp0 = pl[plq + (s0 > 0 ? s0 - 1 : 0)];
        emit += lxq[(2 * c) * 9 + ps0] + lxq[(2 * c + 1) * 9 + ps1];
        const float tv = ltran[pp0 * 9 + ps0];
        trn += (s0 > 0 ? tv : 0.f) + ltran[ps0 * 9 + ps1];
      }

      // hoisted exps for own 3 states x 8 steps
      float e[SPB * 3];
#pragma unroll
      for (int kk = 0; kk < SPB; ++kk)
#pragma unroll
        for (int k = 0; k < 3; ++k)
          e[kk * 3 + k] = fexp(lxq[kk * 9 + myoff + k]);

#pragma unroll
      for (int kk = 0; kk < SPB; ++kk) {
        if (w == 0 && kk == 0) {
#pragma unroll
          for (int k = 0; k < 3; ++k)
            o[k] = (c < 3) ? fexp(initv[3 * c + k]) * e[k] : 0.f;
        } else {
          float nxt[3];
          MATVEC(o)
#pragma unroll
          for (int i = 0; i < 3; ++i) o[i] = nxt[i] * e[kk * 3 + i];
        }
      }
      RESCALE()
    }
  } else {
#pragma unroll 1
    for (int wi = 0; wi < NW; ++wi) {
      const int w = NW - 1 - wi;
      asm volatile("s_waitcnt vmcnt(0)" ::: "memory");
      if (w > 0) { STAGE_X(1152 + 72 * (w - 1), (w - 1) & 1) }
      const float* lxq = &lx[w & 1][q * XSTRIDE];

      // t-parallel gathers: lane c handles t0=128+8w+2c, t1=t0+1
      // slot(t) = t-127; p_{t0-1} at slot 8w+2c (>=0 always)
      {
        const int b0 = 8 * w + 2 * c;
        const int ps0 = pl[plq + b0 + 1];
        const int ps1 = pl[plq + b0 + 2];
        const int pp0 = pl[plq + b0];
        emit += lxq[(2 * c) * 9 + ps0] + lxq[(2 * c + 1) * 9 + ps1];
        trn += ltran[pp0 * 9 + ps0] + ltran[ps0 * 9 + ps1];
      }

      float e[SPB * 3];
#pragma unroll
      for (int kk = 0; kk < SPB; ++kk)
#pragma unroll
        for (int k = 0; k < 3; ++k)
          e[kk * 3 + k] = fexp(lxq[kk * 9 + myoff + k]);

#pragma unroll
      for (int kk = SPB - 1; kk >= 0; --kk) {
        float wv[3];
#pragma unroll
        for (int k = 0; k < 3; ++k) wv[k] = e[kk * 3 + k] * o[k];
        float nxt[3];
        MATVEC(wv)
#pragma unroll
        for (int i = 0; i < 3; ++i) o[i] = nxt[i];
      }
      RESCALE()
    }
  }

  // ---- quad-reduce path score (cyclic rotate-add, quad_perm: proven)
  float tot = emit + trn;
  tot += QROT(tot, QP1);
  tot += QROT(tot, QP2);

  // ---- write partials (field-major)
  float* wp = ws + (seq0 + q);
  if (fwd) {
    if (c < 3) {
#pragma unroll
      for (int k = 0; k < 3; ++k) wp[(3 * c + k) * B_N] = o[k];
    } else {
      wp[9 * B_N] = (float)ce;
      wp[10 * B_N] = tot + initv[pl[plq]];
    }
  } else {
    if (c < 3) {
#pragma unroll
      for (int k = 0; k < 3; ++k) wp[(11 + 3 * c + k) * B_N] = o[k];
    } else {
      wp[20 * B_N] = (float)ce;
      wp[21 * B_N] = tot;
    }
  }
}

__global__ __launch_bounds__(256) void crf_combine(
    const float* __restrict__ ws, float* __restrict__ out)
{
  const int s = blockIdx.x * 256 + threadIdx.x;
  float dot = 0.f;
#pragma unroll
  for (int i = 0; i < 9; ++i)
    dot = fmaf(ws[i * B_N + s], ws[(11 + i) * B_N + s], dot);
  const float score =
      (__builtin_amdgcn_logf(dot) + ws[9 * B_N + s] + ws[20 * B_N + s]) * LN2f;
  out[s] = score - (ws[10 * B_N + s] + ws[21 * B_N + s]);
}

extern "C" void kernel_launch(void* const* d_in, const int* in_sizes, int n_in,
                              void* d_out, int out_size, void* d_ws, size_t ws_size,
                              hipStream_t stream) {
  (void)in_sizes; (void)n_in; (void)out_size; (void)ws_size;
  const float* xg    = (const float*)d_in[0];
  const int*   path  = (const int*)d_in[1];
  const float* tran  = (const float*)d_in[2];
  const float* initv = (const float*)d_in[3];
  float* ws  = (float*)d_ws;    // 22*8192*4 = 721 KB
  float* out = (float*)d_out;

  crf_half<<<2 * NDIR_BLOCKS, 64, 0, stream>>>(xg, path, tran, initv, ws);
  crf_combine<<<B_N / 256, 256, 0, stream>>>(ws, out);
}